// Round 14
// baseline (4413.508 us; speedup 1.0000x reference)
//
#include <hip/hip_runtime.h>
#include <hip/hip_bf16.h>

#define B_ 64
#define S_ 2048
#define T_ 256
#define NB 4   // batches per WG (one barrier interval advances all NB)
#define CPB 4  // chains per batch (16 chains/WG, grid = 4)

typedef __attribute__((ext_vector_type(8))) short bf16x8;
typedef __attribute__((ext_vector_type(4))) float f32x4;

template <int CTRL>
__device__ __forceinline__ float dpp_max(float v) {
  const int t = __builtin_amdgcn_update_dpp(0, __builtin_bit_cast(int, v), CTRL, 0xF, 0xF, true);
  return fmaxf(v, __builtin_bit_cast(float, t));
}
template <int CTRL>
__device__ __forceinline__ float dpp_add(float v) {
  const int t = __builtin_amdgcn_update_dpp(0, __builtin_bit_cast(int, v), CTRL, 0xF, 0xF, true);
  return v + __builtin_bit_cast(float, t);
}

__device__ __forceinline__ unsigned short f2bf(float f) {  // RNE bf16
  unsigned u = __builtin_bit_cast(unsigned, f);
  u += 0x7FFFu + ((u >> 16) & 1u);
  return (unsigned short)(u >> 16);
}

__device__ __forceinline__ f32x4 mfma16(bf16x8 a, bf16x8 b, f32x4 c) {
  return __builtin_amdgcn_mfma_f32_16x16x32_bf16(a, b, c, 0, 0, 0);
}

// lgkm-only barrier: LDS visibility; in-flight global register-prefetch untouched
__device__ __forceinline__ void wg_barrier() {
  __builtin_amdgcn_sched_barrier(0);
  asm volatile("s_waitcnt lgkmcnt(0)" ::: "memory");
  __builtin_amdgcn_s_barrier();
  asm volatile("" ::: "memory");
  __builtin_amdgcn_sched_barrier(0);
}

// ---------------- numerator score: ws[b] ----------------
__global__ void crf_score(const float* __restrict__ em, const int* __restrict__ tags,
                          const int* __restrict__ mask, const float* __restrict__ trans,
                          const float* __restrict__ startt, const float* __restrict__ endt,
                          float* __restrict__ ws) {
  const int b = blockIdx.x;
  const int t = threadIdx.x;  // 256
  const int* tg = tags + b * S_;
  const int* mk = mask + b * S_;
  const float* eb = em + (size_t)b * S_ * T_;

  float sc = 0.f;
  int msum = 0;
  for (int s = t; s < S_; s += 256) {
    const int tag = tg[s];
    const int m = mk[s];
    msum += m;
    const float e = eb[(size_t)s * T_ + tag];
    if (s == 0) {
      sc += startt[tag] + e;
    } else {
      const int pt = tg[s - 1];
      sc += (trans[tag * T_ + pt] + e) * (float)m;
    }
  }
#pragma unroll
  for (int off = 32; off > 0; off >>= 1) {
    sc += __shfl_down(sc, off);
    msum += __shfl_down(msum, off);
  }
  __shared__ float ssc[4];
  __shared__ int smc[4];
  const int wv = t >> 6, ln = t & 63;
  if (ln == 0) { ssc[wv] = sc; smc[wv] = msum; }
  __syncthreads();
  if (t == 0) {
    const float s4 = (ssc[0] + ssc[1]) + (ssc[2] + ssc[3]);
    const int m4 = smc[0] + smc[1] + smc[2] + smc[3];
    const int last = tg[m4 - 1];
    ws[b] = s4 + endt[last];
  }
}

// ---------------- forward (log Z): 4 batches x 4 chains per WG ----------------
// One barrier interval advances ALL 4 batches one step (serial residue amortized
// 4x; independent batches overlap MFMA/VALU/LDS pipes in-order). W-frags shared
// (128 VGPRs). E via per-lane coalesced register prefetch 2 steps ahead (P ring);
// rs folded into exp: EcRs = exp(E + kln), kln = -(ue+8)*ln2 (r11-verified).
// Renorm: exact 1-stale pow2 per batch from post-E stored-x max; integer k_run.
#define STEP(RB, WB, P)                                                           \
  {                                                                               \
    float kln[NB];                                                                \
    _Pragma("unroll") for (int b = 0; b < NB; ++b) {                              \
      const float4 q = ((const float4*)&mpT[RB][b][0])[l & 3];                    \
      float mh = fmaxf(fmaxf(q.x, q.y), fmaxf(q.z, q.w));                         \
      mh = dpp_max<0xB1>(mh);                                                     \
      mh = dpp_max<0x4E>(mh);                                                     \
      int ue = (int)(__builtin_bit_cast(unsigned, mh) >> 23) - 127;               \
      ue = (ue < -20) ? -20 : ue;                                                 \
      ue += 8;                                                                    \
      k_run[b] += ue;                                                             \
      kln[b] = -0.6931471805599453f * (float)ue;                                  \
    }                                                                             \
    float EcRs[NB][4];                                                            \
    _Pragma("unroll") for (int b = 0; b < NB; ++b)                                \
      _Pragma("unroll") for (int r = 0; r < 4; ++r) {                             \
        EcRs[b][r] = __expf(P[b][r] + kln[b]);                                    \
        P[b][r] = emL[cOff[b][r] + rowf];                                         \
      }                                                                           \
    rowf = (rowf < 2047u * 256u) ? rowf + 256u : rowf;                            \
    _Pragma("unroll") for (int b = 0; b < NB; ++b) {                              \
      const unsigned char* xb = &Xl[b][RB][0];                                    \
      f32x4 z4 = {0.f, 0.f, 0.f, 0.f};                                            \
      f32x4 aL0 = z4, aL1 = z4, aL2 = z4, aL3 = z4;                               \
      f32x4 aH0 = z4, aH1 = z4, aH2 = z4, aH3 = z4;                               \
      _Pragma("unroll") for (int kk = 0; kk < 4; ++kk) {                          \
        const bf16x8 av = *(const bf16x8*)(xb + raddr[kk]);                       \
        aL0 = mfma16(av, wf[0][kk], aL0);                                         \
        aL1 = mfma16(av, wf[1][kk], aL1);                                         \
        aL2 = mfma16(av, wf[2][kk], aL2);                                         \
        aL3 = mfma16(av, wf[3][kk], aL3);                                         \
      }                                                                           \
      _Pragma("unroll") for (int kk = 4; kk < 8; ++kk) {                          \
        const bf16x8 av = *(const bf16x8*)(xb + raddr[kk]);                       \
        aH0 = mfma16(av, wf[0][kk], aH0);                                         \
        aH1 = mfma16(av, wf[1][kk], aH1);                                         \
        aH2 = mfma16(av, wf[2][kk], aH2);                                         \
        aH3 = mfma16(av, wf[3][kk], aH3);                                         \
      }                                                                           \
      const f32x4 ac0 = aL0 + aH0, ac1 = aL1 + aH1;                               \
      const f32x4 ac2 = aL2 + aH2, ac3 = aL3 + aH3;                               \
      float xfb[4];                                                               \
      _Pragma("unroll") for (int r = 0; r < 4; ++r) {                             \
        const float s01 = (hi & 1) ? ac1[r] : ac0[r];                             \
        const float s23 = (hi & 1) ? ac3[r] : ac2[r];                             \
        const float val = (hi & 2) ? s23 : s01;                                   \
        xfb[r] = val * EcRs[b][r];                                                \
      }                                                                           \
      float mx = fmaxf(fmaxf(xfb[0], xfb[1]), fmaxf(xfb[2], xfb[3]));             \
      mx = dpp_max<0xB1>(mx);                                                     \
      mx = dpp_max<0x4E>(mx);                                                     \
      mx = dpp_max<0x141>(mx);                                                    \
      mx = dpp_max<0x140>(mx);                                                    \
      if (lo == 0) mpT[WB][b][w * 4 + hi] = mx;                                   \
      _Pragma("unroll") for (int r = 0; r < 4; ++r)                               \
        *(unsigned short*)(&Xl[b][WB][0] + waddr[r]) = f2bf(xfb[r]);              \
    }                                                                             \
    wg_barrier();                                                                 \
  }

__global__ __launch_bounds__(256, 1) void crf_forward(
    const float* __restrict__ em, const float* __restrict__ trans,
    const float* __restrict__ startt, const float* __restrict__ endt,
    float* __restrict__ ws) {
  const int tid = threadIdx.x;
  const int w = tid >> 6;
  const int l = tid & 63;
  const int lo = l & 15;
  const int hi = l >> 4;
  const int c4 = lo & 3;
  const int b0 = blockIdx.x * (NB * CPB);

  __shared__ __align__(16) unsigned char Xl[NB][2][2048];  // x bf16, swizzled
  __shared__ __align__(16) float mpT[2][NB][16];
  __shared__ float fintab[NB][4][4];
  __shared__ float fsum[NB][4];

  // ---- W fragments (B-operand), shared by all batches: 128 VGPRs
  bf16x8 wf[4][8];
#pragma unroll
  for (int t = 0; t < 4; ++t) {
    const int j = 64 * w + 16 * t + lo;
#pragma unroll
    for (int kk = 0; kk < 8; ++kk) {
      bf16x8 v;
#pragma unroll
      for (int e = 0; e < 8; ++e) {
        const int k = kk * 32 + hi * 8 + e;
        v[e] = (short)f2bf(__expf(trans[k * T_ + j]));
      }
      wf[t][kk] = v;
    }
  }

  // ---- addresses (within one 2KB Xl block; unit-XOR swizzle by chain)
  unsigned raddr[8];
#pragma unroll
  for (int kk = 0; kk < 8; ++kk)
    raddr[kk] = (unsigned)(c4 * 512 + 16 * (((4 * kk + hi) ^ (c4 << 2)) & 31));
  const int jE = 64 * w + 16 * hi + lo;  // == 64*w + l
  unsigned waddr[4];
#pragma unroll
  for (int r = 0; r < 4; ++r)
    waddr[r] = (unsigned)(r * 512 + 16 * (((jE >> 3) ^ (r << 2)) & 31) + (jE & 7) * 2);
  const float* emL = em + jE;  // per-lane base (lane-consecutive j -> coalesced)
  unsigned cOff[NB][CPB];      // uniform -> SGPRs
#pragma unroll
  for (int b = 0; b < NB; ++b)
#pragma unroll
    for (int r = 0; r < CPB; ++r)
      cOff[b][r] = (unsigned)((b0 + b * CPB + r) * (S_ * T_));

  // ---- init: al0 = start + em[.,0,.]; exact per-batch max m0[b]
  float m0[NB];
  int k_run[NB];
  const float st = startt[jE];
  {
    float al[NB][4];
#pragma unroll
    for (int b = 0; b < NB; ++b) {
#pragma unroll
      for (int r = 0; r < 4; ++r) al[b][r] = st + emL[cOff[b][r]];
      float lm = fmaxf(fmaxf(al[b][0], al[b][1]), fmaxf(al[b][2], al[b][3]));
      lm = dpp_max<0xB1>(lm);
      lm = dpp_max<0x4E>(lm);
      lm = dpp_max<0x141>(lm);
      lm = dpp_max<0x140>(lm);
      lm = fmaxf(lm, __shfl_xor(lm, 16));
      lm = fmaxf(lm, __shfl_xor(lm, 32));
      if (l == 0) fsum[b][w] = lm;
    }
    __syncthreads();
#pragma unroll
    for (int b = 0; b < NB; ++b) {
      m0[b] = fmaxf(fmaxf(fsum[b][0], fsum[b][1]), fmaxf(fsum[b][2], fsum[b][3]));
#pragma unroll
      for (int r = 0; r < 4; ++r) {
        const float x0 = __expf(al[b][r] - m0[b]);
        *(unsigned short*)(&Xl[b][0][0] + waddr[r]) = f2bf(x0);
      }
      k_run[b] = 0;
    }
    if (tid < 64) mpT[0][tid >> 4][tid & 15] = 1.0f;  // max(x0) == 1 exactly
  }
  // ---- E register prefetch ring: P0 = row 1, P1 = row 2; next load row 3
  float P0[NB][4], P1[NB][4];
#pragma unroll
  for (int b = 0; b < NB; ++b)
#pragma unroll
    for (int r = 0; r < 4; ++r) {
      P0[b][r] = emL[cOff[b][r] + 256];
      P1[b][r] = emL[cOff[b][r] + 512];
    }
  unsigned rowf = 3u * 256u;
  __syncthreads();

  // ---- main loop: steps 1..2046 as pairs, tail 2047
  for (int p2 = 0; p2 < (S_ - 2) / 2; ++p2) {
    STEP(0, 1, P0)
    STEP(1, 0, P1)
  }

  // ---- tail step s = 2047 (RB = 0, uses P0): no store, no barrier
  float xtail[NB][4];
  {
#pragma unroll
    for (int b = 0; b < NB; ++b) {
      const float4 q = ((const float4*)&mpT[0][b][0])[l & 3];
      float mh = fmaxf(fmaxf(q.x, q.y), fmaxf(q.z, q.w));
      mh = dpp_max<0xB1>(mh);
      mh = dpp_max<0x4E>(mh);
      int ue = (int)(__builtin_bit_cast(unsigned, mh) >> 23) - 127;
      ue = (ue < -20) ? -20 : ue;
      ue += 8;
      k_run[b] += ue;
      const float kln = -0.6931471805599453f * (float)ue;
      float EcRs[4];
#pragma unroll
      for (int r = 0; r < 4; ++r) EcRs[r] = __expf(P0[b][r] + kln);
      const unsigned char* xb = &Xl[b][0][0];
      f32x4 z4 = {0.f, 0.f, 0.f, 0.f};
      f32x4 aL0 = z4, aL1 = z4, aL2 = z4, aL3 = z4;
      f32x4 aH0 = z4, aH1 = z4, aH2 = z4, aH3 = z4;
#pragma unroll
      for (int kk = 0; kk < 4; ++kk) {
        const bf16x8 av = *(const bf16x8*)(xb + raddr[kk]);
        aL0 = mfma16(av, wf[0][kk], aL0);
        aL1 = mfma16(av, wf[1][kk], aL1);
        aL2 = mfma16(av, wf[2][kk], aL2);
        aL3 = mfma16(av, wf[3][kk], aL3);
      }
#pragma unroll
      for (int kk = 4; kk < 8; ++kk) {
        const bf16x8 av = *(const bf16x8*)(xb + raddr[kk]);
        aH0 = mfma16(av, wf[0][kk], aH0);
        aH1 = mfma16(av, wf[1][kk], aH1);
        aH2 = mfma16(av, wf[2][kk], aH2);
        aH3 = mfma16(av, wf[3][kk], aH3);
      }
      const f32x4 ac0 = aL0 + aH0, ac1 = aL1 + aH1;
      const f32x4 ac2 = aL2 + aH2, ac3 = aL3 + aH3;
#pragma unroll
      for (int r = 0; r < 4; ++r) {
        const float s01 = (hi & 1) ? ac1[r] : ac0[r];
        const float s23 = (hi & 1) ? ac3[r] : ac2[r];
        const float val = (hi & 2) ? s23 : s01;
        xtail[b][r] = val * EcRs[r];
      }
    }
  }

  // ---- epilogue: logZ[c] = m0[b] + k_run[b]*ln2 + log(sum_j x*exp(end_j))
  const float ee = __expf(endt[jE]);
#pragma unroll
  for (int b = 0; b < NB; ++b) {
    float fr[4];
#pragma unroll
    for (int r = 0; r < 4; ++r) {
      float f = xtail[b][r] * ee;
      f = dpp_add<0xB1>(f);
      f = dpp_add<0x4E>(f);
      f = dpp_add<0x141>(f);
      f = dpp_add<0x140>(f);
      f += __shfl_xor(f, 16);
      f += __shfl_xor(f, 32);
      fr[r] = f;
    }
    if (l == 0) {
      float4 fv;
      fv.x = fr[0]; fv.y = fr[1]; fv.z = fr[2]; fv.w = fr[3];
      *(float4*)&fintab[b][w][0] = fv;
    }
  }
  __syncthreads();
  if (tid < NB * CPB) {
    const int b = tid >> 2, r = tid & 3;
    const float tot = (fintab[b][0][r] + fintab[b][1][r]) +
                      (fintab[b][2][r] + fintab[b][3][r]);
    ws[64 + b0 + tid] = m0[b] + (float)k_run[b] * 0.6931471805599453f + __logf(tot);
  }
}

// ---------------- final: mean_b(score - logZ) ----------------
__global__ void crf_final(const float* __restrict__ ws, float* __restrict__ out) {
  const int t = threadIdx.x;  // 64
  float v = ws[t] - ws[64 + t];
#pragma unroll
  for (int off = 1; off <= 32; off <<= 1) v += __shfl_xor(v, off);
  if (t == 0) out[0] = v * (1.0f / 64.0f);
}

extern "C" void kernel_launch(void* const* d_in, const int* in_sizes, int n_in,
                              void* d_out, int out_size, void* d_ws, size_t ws_size,
                              hipStream_t stream) {
  const float* em = (const float*)d_in[0];
  const int* tags = (const int*)d_in[1];
  const int* mask = (const int*)d_in[2];
  const float* trans = (const float*)d_in[3];
  const float* startt = (const float*)d_in[4];
  const float* endt = (const float*)d_in[5];
  float* out = (float*)d_out;
  float* ws = (float*)d_ws;

  crf_score<<<B_, 256, 0, stream>>>(em, tags, mask, trans, startt, endt, ws);
  crf_forward<<<B_ / (NB * CPB), 256, 0, stream>>>(em, trans, startt, endt, ws);
  crf_final<<<1, 64, 0, stream>>>(ws, out);
}

// Round 15
// 973.914 us; speedup vs baseline: 4.5317x; 4.5317x over previous
//
#include <hip/hip_runtime.h>
#include <hip/hip_bf16.h>

#define B_ 64
#define S_ 2048
#define T_ 256

typedef __attribute__((ext_vector_type(8))) short bf16x8;
typedef __attribute__((ext_vector_type(4))) float f32x4;

template <int CTRL>
__device__ __forceinline__ float dpp_max(float v) {
  const int t = __builtin_amdgcn_update_dpp(0, __builtin_bit_cast(int, v), CTRL, 0xF, 0xF, true);
  return fmaxf(v, __builtin_bit_cast(float, t));
}
template <int CTRL>
__device__ __forceinline__ float dpp_add(float v) {
  const int t = __builtin_amdgcn_update_dpp(0, __builtin_bit_cast(int, v), CTRL, 0xF, 0xF, true);
  return v + __builtin_bit_cast(float, t);
}

__device__ __forceinline__ unsigned short f2bf(float f) {  // RNE bf16
  unsigned u = __builtin_bit_cast(unsigned, f);
  u += 0x7FFFu + ((u >> 16) & 1u);
  return (unsigned short)(u >> 16);
}

__device__ __forceinline__ f32x4 mfma16(bf16x8 a, bf16x8 b, f32x4 c) {
  return __builtin_amdgcn_mfma_f32_16x16x32_bf16(a, b, c, 0, 0, 0);
}

// lgkm-only barrier: LDS visibility; in-flight global register-prefetch untouched
__device__ __forceinline__ void wg_barrier() {
  __builtin_amdgcn_sched_barrier(0);
  asm volatile("s_waitcnt lgkmcnt(0)" ::: "memory");
  __builtin_amdgcn_s_barrier();
  asm volatile("" ::: "memory");
  __builtin_amdgcn_sched_barrier(0);
}

// ---------------- numerator score: ws[b] ----------------
__global__ void crf_score(const float* __restrict__ em, const int* __restrict__ tags,
                          const int* __restrict__ mask, const float* __restrict__ trans,
                          const float* __restrict__ startt, const float* __restrict__ endt,
                          float* __restrict__ ws) {
  const int b = blockIdx.x;
  const int t = threadIdx.x;  // 256
  const int* tg = tags + b * S_;
  const int* mk = mask + b * S_;
  const float* eb = em + (size_t)b * S_ * T_;

  float sc = 0.f;
  int msum = 0;
  for (int s = t; s < S_; s += 256) {
    const int tag = tg[s];
    const int m = mk[s];
    msum += m;
    const float e = eb[(size_t)s * T_ + tag];
    if (s == 0) {
      sc += startt[tag] + e;
    } else {
      const int pt = tg[s - 1];
      sc += (trans[tag * T_ + pt] + e) * (float)m;
    }
  }
#pragma unroll
  for (int off = 32; off > 0; off >>= 1) {
    sc += __shfl_down(sc, off);
    msum += __shfl_down(msum, off);
  }
  __shared__ float ssc[4];
  __shared__ int smc[4];
  const int wv = t >> 6, ln = t & 63;
  if (ln == 0) { ssc[wv] = sc; smc[wv] = msum; }
  __syncthreads();
  if (t == 0) {
    const float s4 = (ssc[0] + ssc[1]) + (ssc[2] + ssc[3]);
    const int m4 = smc[0] + smc[1] + smc[2] + smc[3];
    const int last = tg[m4 - 1];
    ws[b] = s4 + endt[last];
  }
}

// ---------------- forward (log Z): ONE chain per WG, 64 WGs ----------------
// Minimal per-CU issue at max chain spread. All 16 A-tile rows alias chain 0:
// every lane reads the single 512B X row (broadcast; 4 distinct addrs/instr).
// Lane (lo,hi) of wave w owns output j = 64w+16hi+lo: D-tile selected by hi
// (cndmask), reg 0 (all D rows = chain 0). Per-thread epilogue: 1 exp (rs
// folded: EcRs = exp(E + kln)), 1 E-prefetch load (2-step P ring), scalar max,
// 1 f2bf, 1 ds_write_b16. Renorm: exact 1-stale pow2 from post-E stored-x max;
// integer k_run (r11-proven numerics).
#define STEP(RB, WB, P)                                                           \
  {                                                                               \
    const float4 q = ((const float4*)&mpT[RB][0])[l & 3];                         \
    float mh = fmaxf(fmaxf(q.x, q.y), fmaxf(q.z, q.w));                           \
    mh = dpp_max<0xB1>(mh);                                                       \
    mh = dpp_max<0x4E>(mh);                                                       \
    int ue = (int)(__builtin_bit_cast(unsigned, mh) >> 23) - 127;                 \
    ue = (ue < -20) ? -20 : ue;                                                   \
    ue += 8;                                                                      \
    k_run += ue;                                                                  \
    const float kln = -0.6931471805599453f * (float)ue;                           \
    const float EcRs = __expf(P + kln);                                           \
    P = emL[cOff + rowf];                                                         \
    rowf = (rowf < 2047u * 256u) ? rowf + 256u : rowf;                            \
    const unsigned char* xb = &Xl[RB][0];                                         \
    f32x4 z4 = {0.f, 0.f, 0.f, 0.f};                                              \
    f32x4 aL0 = z4, aL1 = z4, aL2 = z4, aL3 = z4;                                 \
    f32x4 aH0 = z4, aH1 = z4, aH2 = z4, aH3 = z4;                                 \
    _Pragma("unroll") for (int kk = 0; kk < 4; ++kk) {                            \
      const bf16x8 av = *(const bf16x8*)(xb + raddr[kk]);                         \
      aL0 = mfma16(av, wf[0][kk], aL0);                                           \
      aL1 = mfma16(av, wf[1][kk], aL1);                                           \
      aL2 = mfma16(av, wf[2][kk], aL2);                                           \
      aL3 = mfma16(av, wf[3][kk], aL3);                                           \
    }                                                                             \
    _Pragma("unroll") for (int kk = 4; kk < 8; ++kk) {                            \
      const bf16x8 av = *(const bf16x8*)(xb + raddr[kk]);                         \
      aH0 = mfma16(av, wf[0][kk], aH0);                                           \
      aH1 = mfma16(av, wf[1][kk], aH1);                                           \
      aH2 = mfma16(av, wf[2][kk], aH2);                                           \
      aH3 = mfma16(av, wf[3][kk], aH3);                                           \
    }                                                                             \
    const float c0 = aL0[0] + aH0[0], c1 = aL1[0] + aH1[0];                       \
    const float c2 = aL2[0] + aH2[0], c3 = aL3[0] + aH3[0];                       \
    const float s01 = (hi & 1) ? c1 : c0;                                         \
    const float s23 = (hi & 1) ? c3 : c2;                                         \
    const float val = (hi & 2) ? s23 : s01;                                       \
    const float xfb = val * EcRs;                                                 \
    float mx = xfb;                                                               \
    mx = dpp_max<0xB1>(mx);                                                       \
    mx = dpp_max<0x4E>(mx);                                                       \
    mx = dpp_max<0x141>(mx);                                                      \
    mx = dpp_max<0x140>(mx);                                                      \
    if (lo == 0) mpT[WB][w * 4 + hi] = mx;                                        \
    *(unsigned short*)(&Xl[WB][0] + waddr) = f2bf(xfb);                           \
    wg_barrier();                                                                 \
  }

__global__ __launch_bounds__(256, 1) void crf_forward(
    const float* __restrict__ em, const float* __restrict__ trans,
    const float* __restrict__ startt, const float* __restrict__ endt,
    float* __restrict__ ws) {
  const int tid = threadIdx.x;
  const int w = tid >> 6;
  const int l = tid & 63;
  const int lo = l & 15;
  const int hi = l >> 4;

  __shared__ __align__(16) unsigned char Xl[2][512];  // x bf16, one 256-wide row
  __shared__ __align__(16) float mpT[2][16];
  __shared__ float fsum[4];

  // ---- W fragments (B-operand): 128 VGPRs
  bf16x8 wf[4][8];
#pragma unroll
  for (int t = 0; t < 4; ++t) {
    const int j = 64 * w + 16 * t + lo;
#pragma unroll
    for (int kk = 0; kk < 8; ++kk) {
      bf16x8 v;
#pragma unroll
      for (int e = 0; e < 8; ++e) {
        const int k = kk * 32 + hi * 8 + e;
        v[e] = (short)f2bf(__expf(trans[k * T_ + j]));
      }
      wf[t][kk] = v;
    }
  }

  // ---- addresses: all A rows alias chain 0 (single 512B row, no row offset)
  unsigned raddr[8];
#pragma unroll
  for (int kk = 0; kk < 8; ++kk) raddr[kk] = (unsigned)(16 * ((4 * kk + hi) & 31));
  const int jE = 64 * w + 16 * hi + lo;  // == 64*w + l
  const unsigned waddr = (unsigned)(16 * ((jE >> 3) & 31) + (jE & 7) * 2);
  const float* emL = em + jE;  // lane-consecutive j -> coalesced
  const unsigned cOff = (unsigned)(blockIdx.x * (S_ * T_));

  // ---- init: al0 = start + em[.,0,.]; exact max m0
  float m0;
  {
    const float al = startt[jE] + emL[cOff];
    float lm = al;
    lm = dpp_max<0xB1>(lm);
    lm = dpp_max<0x4E>(lm);
    lm = dpp_max<0x141>(lm);
    lm = dpp_max<0x140>(lm);
    lm = fmaxf(lm, __shfl_xor(lm, 16));
    lm = fmaxf(lm, __shfl_xor(lm, 32));
    if (l == 0) fsum[w] = lm;
    __syncthreads();
    m0 = fmaxf(fmaxf(fsum[0], fsum[1]), fmaxf(fsum[2], fsum[3]));
    const float x0 = __expf(al - m0);
    *(unsigned short*)(&Xl[0][0] + waddr) = f2bf(x0);
    if (tid < 16) mpT[0][tid] = 1.0f;  // max(x0) == 1 exactly
  }
  // ---- E register prefetch ring: P0 = row 1, P1 = row 2; next load row 3
  float P0 = emL[cOff + 256];
  float P1 = emL[cOff + 512];
  unsigned rowf = 3u * 256u;
  int k_run = 0;
  __syncthreads();

  // ---- main loop: steps 1..2046 as pairs, tail 2047
  for (int p2 = 0; p2 < (S_ - 2) / 2; ++p2) {
    STEP(0, 1, P0)
    STEP(1, 0, P1)
  }

  // ---- tail step s = 2047 (RB = 0, uses P0): no store, no barrier
  float xtail;
  {
    const float4 q = ((const float4*)&mpT[0][0])[l & 3];
    float mh = fmaxf(fmaxf(q.x, q.y), fmaxf(q.z, q.w));
    mh = dpp_max<0xB1>(mh);
    mh = dpp_max<0x4E>(mh);
    int ue = (int)(__builtin_bit_cast(unsigned, mh) >> 23) - 127;
    ue = (ue < -20) ? -20 : ue;
    ue += 8;
    k_run += ue;
    const float kln = -0.6931471805599453f * (float)ue;
    const float EcRs = __expf(P0 + kln);
    const unsigned char* xb = &Xl[0][0];
    f32x4 z4 = {0.f, 0.f, 0.f, 0.f};
    f32x4 aL0 = z4, aL1 = z4, aL2 = z4, aL3 = z4;
    f32x4 aH0 = z4, aH1 = z4, aH2 = z4, aH3 = z4;
#pragma unroll
    for (int kk = 0; kk < 4; ++kk) {
      const bf16x8 av = *(const bf16x8*)(xb + raddr[kk]);
      aL0 = mfma16(av, wf[0][kk], aL0);
      aL1 = mfma16(av, wf[1][kk], aL1);
      aL2 = mfma16(av, wf[2][kk], aL2);
      aL3 = mfma16(av, wf[3][kk], aL3);
    }
#pragma unroll
    for (int kk = 4; kk < 8; ++kk) {
      const bf16x8 av = *(const bf16x8*)(xb + raddr[kk]);
      aH0 = mfma16(av, wf[0][kk], aH0);
      aH1 = mfma16(av, wf[1][kk], aH1);
      aH2 = mfma16(av, wf[2][kk], aH2);
      aH3 = mfma16(av, wf[3][kk], aH3);
    }
    const float c0 = aL0[0] + aH0[0], c1 = aL1[0] + aH1[0];
    const float c2 = aL2[0] + aH2[0], c3 = aL3[0] + aH3[0];
    const float s01 = (hi & 1) ? c1 : c0;
    const float s23 = (hi & 1) ? c3 : c2;
    const float val = (hi & 2) ? s23 : s01;
    xtail = val * EcRs;
  }

  // ---- epilogue: logZ = m0 + k_run*ln2 + log(sum_j x[j]*exp(end[j]))
  float f = xtail * __expf(endt[jE]);
  f = dpp_add<0xB1>(f);
  f = dpp_add<0x4E>(f);
  f = dpp_add<0x141>(f);
  f = dpp_add<0x140>(f);
  f += __shfl_xor(f, 16);
  f += __shfl_xor(f, 32);
  __syncthreads();  // fsum reuse
  if (l == 0) fsum[w] = f;
  __syncthreads();
  if (tid == 0) {
    const float tot = (fsum[0] + fsum[1]) + (fsum[2] + fsum[3]);
    ws[64 + blockIdx.x] = m0 + (float)k_run * 0.6931471805599453f + __logf(tot);
  }
}

// ---------------- final: mean_b(score - logZ) ----------------
__global__ void crf_final(const float* __restrict__ ws, float* __restrict__ out) {
  const int t = threadIdx.x;  // 64
  float v = ws[t] - ws[64 + t];
#pragma unroll
  for (int off = 1; off <= 32; off <<= 1) v += __shfl_xor(v, off);
  if (t == 0) out[0] = v * (1.0f / 64.0f);
}

extern "C" void kernel_launch(void* const* d_in, const int* in_sizes, int n_in,
                              void* d_out, int out_size, void* d_ws, size_t ws_size,
                              hipStream_t stream) {
  const float* em = (const float*)d_in[0];
  const int* tags = (const int*)d_in[1];
  const int* mask = (const int*)d_in[2];
  const float* trans = (const float*)d_in[3];
  const float* startt = (const float*)d_in[4];
  const float* endt = (const float*)d_in[5];
  float* out = (float*)d_out;
  float* ws = (float*)d_ws;

  crf_score<<<B_, 256, 0, stream>>>(em, tags, mask, trans, startt, endt, ws);
  crf_forward<<<B_, 256, 0, stream>>>(em, trans, startt, endt, ws);
  crf_final<<<1, 64, 0, stream>>>(ws, out);
}